// Round 2
// baseline (889.866 us; speedup 1.0000x reference)
//
#include <hip/hip_runtime.h>
#include <hip/hip_bf16.h>

#define NNODES 100000
#define NEDGES 1600000
#define IN_CH 128
#define HID 64
#define NC 40

// ---- degree / norm ----
__global__ void k_deg_init(float* __restrict__ deg, int n) {
    int i = blockIdx.x * blockDim.x + threadIdx.x;
    if (i < n) deg[i] = 1.0f;  // self-loop
}
__global__ void k_deg_count(const int* __restrict__ dsts, float* __restrict__ deg, int e) {
    int i = blockIdx.x * blockDim.x + threadIdx.x;
    if (i < e) atomicAdd(&deg[dsts[i]], 1.0f);
}
__global__ void k_dinv(float* __restrict__ deg, int n) {
    int i = blockIdx.x * blockDim.x + threadIdx.x;
    if (i < n) deg[i] = rsqrtf(deg[i]);  // deg >= 1 always (self-loops)
}

// ---- GEMM1: hw1 = x @ W1 (f32 vector ALU, W1 in LDS); agg1 = hw1 * dinv^2 ----
__global__ __launch_bounds__(256) void k_gemm1(
    const float* __restrict__ x, const float* __restrict__ W1,
    const float* __restrict__ dinv, float* __restrict__ hw1, float* __restrict__ agg1, int n)
{
    __shared__ float wsm[IN_CH * HID];  // 32 KB
    for (int i = threadIdx.x; i < IN_CH * HID; i += 256) wsm[i] = W1[i];
    __syncthreads();
    int row = blockIdx.x * 256 + threadIdx.x;
    if (row >= n) return;
    const float4* xr = (const float4*)(x + (size_t)row * IN_CH);
    float acc[HID];
#pragma unroll
    for (int c = 0; c < HID; ++c) acc[c] = 0.f;
#pragma unroll 4
    for (int k4 = 0; k4 < IN_CH / 4; ++k4) {
        float4 xv = xr[k4];  // coalesced within wave? (stride 128f) — L2/L3 served
        const float* w0 = wsm + (k4 * 4) * HID;
#pragma unroll
        for (int c = 0; c < HID; ++c)
            acc[c] += xv.x * w0[c] + xv.y * w0[c + HID] + xv.z * w0[c + 2 * HID] + xv.w * w0[c + 3 * HID];
    }
    float di = dinv[row];
    float sl = di * di;
    float* o1 = hw1 + (size_t)row * HID;
    float* o2 = agg1 + (size_t)row * HID;
#pragma unroll
    for (int c = 0; c < HID; ++c) {
        o1[c] = acc[c];
        o2[c] = acc[c] * sl;  // self-loop contribution initializes agg1
    }
}

// ---- edge scatter layer 1: one wave per edge, lane = feature ----
__global__ __launch_bounds__(256) void k_edge1(
    const int* __restrict__ srcs, const int* __restrict__ dsts, const float* __restrict__ dinv,
    const float* __restrict__ hw1, float* __restrict__ agg1, int e)
{
    int eid = blockIdx.x * 4 + (threadIdx.x >> 6);
    if (eid >= e) return;
    int lane = threadIdx.x & 63;
    int s = srcs[eid];
    int d = dsts[eid];
    float nrm = dinv[s] * dinv[d];
    float v = hw1[(size_t)s * HID + lane] * nrm;
    atomicAdd(&agg1[(size_t)d * HID + lane], v);
}

// ---- h = relu(agg1 + b1), in place ----
__global__ void k_relu_bias(float* __restrict__ agg1, const float* __restrict__ b1, int total) {
    int i = blockIdx.x * blockDim.x + threadIdx.x;
    if (i < total) {
        float v = agg1[i] + b1[i & (HID - 1)];
        agg1[i] = v > 0.f ? v : 0.f;
    }
}

// ---- GEMM2: hw2 = h @ W2 (f32 vector ALU, W2 in LDS); agg2 = hw2 * dinv^2 ----
__global__ __launch_bounds__(256) void k_gemm2(
    const float* __restrict__ h, const float* __restrict__ W2,
    const float* __restrict__ dinv, float* __restrict__ hw2, float* __restrict__ agg2, int n)
{
    __shared__ float wsm[HID * NC];  // 10 KB
    for (int i = threadIdx.x; i < HID * NC; i += 256) wsm[i] = W2[i];
    __syncthreads();
    int row = blockIdx.x * 256 + threadIdx.x;
    if (row >= n) return;
    const float4* hr = (const float4*)(h + (size_t)row * HID);
    float acc[NC];
#pragma unroll
    for (int c = 0; c < NC; ++c) acc[c] = 0.f;
#pragma unroll 4
    for (int k4 = 0; k4 < HID / 4; ++k4) {
        float4 hv = hr[k4];
        const float* w0 = wsm + (k4 * 4) * NC;
#pragma unroll
        for (int c = 0; c < NC; ++c)
            acc[c] += hv.x * w0[c] + hv.y * w0[c + NC] + hv.z * w0[c + 2 * NC] + hv.w * w0[c + 3 * NC];
    }
    float di = dinv[row];
    float sl = di * di;
    float* o1 = hw2 + (size_t)row * NC;
    float* o2 = agg2 + (size_t)row * NC;
#pragma unroll
    for (int c = 0; c < NC; ++c) {
        o1[c] = acc[c];
        o2[c] = acc[c] * sl;
    }
}

// ---- edge scatter layer 2: flat (edge, feat) mapping ----
__global__ __launch_bounds__(256) void k_edge2(
    const int* __restrict__ srcs, const int* __restrict__ dsts, const float* __restrict__ dinv,
    const float* __restrict__ hw2, float* __restrict__ agg2, long long total)
{
    long long idx = (long long)blockIdx.x * blockDim.x + threadIdx.x;
    if (idx >= total) return;
    unsigned int e = (unsigned int)(idx / NC);
    unsigned int c = (unsigned int)(idx - (long long)e * NC);
    int s = srcs[e];
    int d = dsts[e];
    float nrm = dinv[s] * dinv[d];
    float v = hw2[(size_t)s * NC + c] * nrm;
    atomicAdd(&agg2[(size_t)d * NC + c], v);
}

// ---- out = agg2 + b2 (f32) ----
__global__ void k_out(const float* __restrict__ agg2, const float* __restrict__ b2,
                      float* __restrict__ out, int total) {
    int i = blockIdx.x * blockDim.x + threadIdx.x;
    if (i < total) {
        unsigned int c = (unsigned int)i % NC;
        out[i] = agg2[i] + b2[c];
    }
}

extern "C" void kernel_launch(void* const* d_in, const int* in_sizes, int n_in,
                              void* d_out, int out_size, void* d_ws, size_t ws_size,
                              hipStream_t stream) {
    const float* x  = (const float*)d_in[0];   // f32 [N,128]
    const int* edge = (const int*)d_in[1];     // int32 [2,E]
    const float* W1 = (const float*)d_in[2];   // f32 [128,64]
    const float* b1 = (const float*)d_in[3];   // f32 [64]
    const float* W2 = (const float*)d_in[4];   // f32 [64,40]
    const float* b2 = (const float*)d_in[5];   // f32 [40]
    float* out      = (float*)d_out;           // f32 [N,40]

    const int n = in_sizes[0] / IN_CH;   // 100000
    const int e = in_sizes[1] / 2;       // 1600000
    const int* srcs = edge;
    const int* dsts = edge + e;

    // workspace layout (f32): dinv | hw1 | agg1 | hw2 | agg2  = ~83.6 MB
    float* ws   = (float*)d_ws;
    float* deg  = ws;                          // n (becomes dinv in place)
    float* hw1  = ws + 100096;                 // n*64
    float* agg1 = hw1 + (size_t)NNODES * HID;  // n*64
    float* hw2  = agg1 + (size_t)NNODES * HID; // n*40
    float* agg2 = hw2 + (size_t)NNODES * NC;   // n*40

    k_deg_init<<<(n + 255) / 256, 256, 0, stream>>>(deg, n);
    k_deg_count<<<(e + 255) / 256, 256, 0, stream>>>(dsts, deg, e);
    k_dinv<<<(n + 255) / 256, 256, 0, stream>>>(deg, n);

    k_gemm1<<<(n + 255) / 256, 256, 0, stream>>>(x, W1, deg, hw1, agg1, n);
    k_edge1<<<(e + 3) / 4, 256, 0, stream>>>(srcs, dsts, deg, hw1, agg1, e);
    k_relu_bias<<<(n * HID + 255) / 256, 256, 0, stream>>>(agg1, b1, n * HID);

    k_gemm2<<<(n + 255) / 256, 256, 0, stream>>>(agg1, W2, deg, hw2, agg2, n);
    long long tot2 = (long long)e * NC;
    k_edge2<<<(unsigned int)((tot2 + 255) / 256), 256, 0, stream>>>(srcs, dsts, deg, hw2, agg2, tot2);
    k_out<<<(n * NC + 255) / 256, 256, 0, stream>>>(agg2, b2, out, n * NC);
}

// Round 3
// 536.475 us; speedup vs baseline: 1.6587x; 1.6587x over previous
//
#include <hip/hip_runtime.h>
#include <hip/hip_bf16.h>

#define NNODES 100000
#define NEDGES 1600000
#define IN_CH 128
#define HID 64
#define NC 40
#define NPAD 100352   // NNODES padded to multiple of 256

// ---- CSR build: histogram of dst ----
__global__ void k_hist(const int* __restrict__ dsts, int* __restrict__ counts, int e) {
    int i = blockIdx.x * blockDim.x + threadIdx.x;
    if (i < e) atomicAdd(&counts[dsts[i]], 1);
}

// block-local exclusive scan (256 wide), block totals to partials
__global__ __launch_bounds__(256) void k_scan1(const int* __restrict__ counts,
                                               int* __restrict__ excl, int* __restrict__ partials, int n) {
    __shared__ int s[256];
    int t = threadIdx.x;
    int i = blockIdx.x * 256 + t;
    int c = (i < n) ? counts[i] : 0;
    s[t] = c;
    __syncthreads();
    for (int off = 1; off < 256; off <<= 1) {
        int v = (t >= off) ? s[t - off] : 0;
        __syncthreads();
        s[t] += v;
        __syncthreads();
    }
    if (i < n) excl[i] = s[t] - c;
    if (t == 255) partials[blockIdx.x] = s[t];
}

// scan the 391 block totals (single block, Hillis-Steele in LDS)
__global__ __launch_bounds__(512) void k_scan2(int* __restrict__ partials, int nb) {
    __shared__ int s[512];
    int t = threadIdx.x;
    int c = (t < nb) ? partials[t] : 0;
    s[t] = c;
    __syncthreads();
    for (int off = 1; off < 512; off <<= 1) {
        int v = (t >= off) ? s[t - off] : 0;
        __syncthreads();
        s[t] += v;
        __syncthreads();
    }
    if (t < nb) partials[t] = s[t] - c;  // exclusive
}

// fixup: final row_start, cursor copy, dinv from counts (+1 self-loop)
__global__ void k_scan3(const int* __restrict__ counts, const int* __restrict__ partials,
                        int* __restrict__ row_start, int* __restrict__ cursor,
                        float* __restrict__ dinv, int n, int e) {
    int i = blockIdx.x * blockDim.x + threadIdx.x;
    if (i < n) {
        int rs = row_start[i] + partials[i >> 8];
        row_start[i] = rs;
        cursor[i] = rs;
        dinv[i] = rsqrtf((float)counts[i] + 1.0f);
        if (i == 0) row_start[n] = e;
    }
}

// rank-scatter edges into dst-sorted order
__global__ void k_scatter(const int* __restrict__ srcs, const int* __restrict__ dsts,
                          int* __restrict__ cursor, int* __restrict__ sorted_src, int e) {
    int i = blockIdx.x * blockDim.x + threadIdx.x;
    if (i < e) {
        int d = dsts[i];
        int pos = atomicAdd(&cursor[d], 1);
        sorted_src[pos] = srcs[i];
    }
}

// ---- GEMM1: hw1 = x @ W1 (f32 vector ALU, W1 in LDS) ----
__global__ __launch_bounds__(256) void k_gemm1(
    const float* __restrict__ x, const float* __restrict__ W1,
    float* __restrict__ hw1, int n)
{
    __shared__ float wsm[IN_CH * HID];  // 32 KB
    for (int i = threadIdx.x; i < IN_CH * HID; i += 256) wsm[i] = W1[i];
    __syncthreads();
    int row = blockIdx.x * 256 + threadIdx.x;
    if (row >= n) return;
    const float4* xr = (const float4*)(x + (size_t)row * IN_CH);
    float acc[HID];
#pragma unroll
    for (int c = 0; c < HID; ++c) acc[c] = 0.f;
#pragma unroll 4
    for (int k4 = 0; k4 < IN_CH / 4; ++k4) {
        float4 xv = xr[k4];
        const float* w0 = wsm + (k4 * 4) * HID;
#pragma unroll
        for (int c = 0; c < HID; ++c)
            acc[c] += xv.x * w0[c] + xv.y * w0[c + HID] + xv.z * w0[c + 2 * HID] + xv.w * w0[c + 3 * HID];
    }
    float* o1 = hw1 + (size_t)row * HID;
#pragma unroll
    for (int c = 0; c < HID; ++c) o1[c] = acc[c];
}

// ---- aggregation layer 1: one wave per node, lane = feature; fused bias+relu ----
__global__ __launch_bounds__(256) void k_agg1(
    const int* __restrict__ row_start, const int* __restrict__ sorted_src,
    const float* __restrict__ dinv, const float* __restrict__ hw1,
    const float* __restrict__ b1, float* __restrict__ h, int n)
{
    int node = blockIdx.x * 4 + (threadIdx.x >> 6);
    if (node >= n) return;
    int lane = threadIdx.x & 63;
    int rs = row_start[node];
    int re = row_start[node + 1];
    float di = dinv[node];
    float acc = hw1[(size_t)node * HID + lane] * di * di;  // self-loop
    int k = rs;
    for (; k + 1 < re; k += 2) {
        int s0 = sorted_src[k];
        int s1 = sorted_src[k + 1];
        float w0 = dinv[s0] * di;
        float w1 = dinv[s1] * di;
        float v0 = hw1[(size_t)s0 * HID + lane];
        float v1 = hw1[(size_t)s1 * HID + lane];
        acc += v0 * w0 + v1 * w1;
    }
    if (k < re) {
        int s0 = sorted_src[k];
        acc += hw1[(size_t)s0 * HID + lane] * dinv[s0] * di;
    }
    float v = acc + b1[lane];
    h[(size_t)node * HID + lane] = v > 0.f ? v : 0.f;
}

// ---- GEMM2: hw2 = h @ W2 (f32 vector ALU, W2 in LDS) ----
__global__ __launch_bounds__(256) void k_gemm2(
    const float* __restrict__ h, const float* __restrict__ W2,
    float* __restrict__ hw2, int n)
{
    __shared__ float wsm[HID * NC];  // 10 KB
    for (int i = threadIdx.x; i < HID * NC; i += 256) wsm[i] = W2[i];
    __syncthreads();
    int row = blockIdx.x * 256 + threadIdx.x;
    if (row >= n) return;
    const float4* hr = (const float4*)(h + (size_t)row * HID);
    float acc[NC];
#pragma unroll
    for (int c = 0; c < NC; ++c) acc[c] = 0.f;
#pragma unroll 4
    for (int k4 = 0; k4 < HID / 4; ++k4) {
        float4 hv = hr[k4];
        const float* w0 = wsm + (k4 * 4) * NC;
#pragma unroll
        for (int c = 0; c < NC; ++c)
            acc[c] += hv.x * w0[c] + hv.y * w0[c + NC] + hv.z * w0[c + 2 * NC] + hv.w * w0[c + 3 * NC];
    }
    float* o1 = hw2 + (size_t)row * NC;
#pragma unroll
    for (int c = 0; c < NC; ++c) o1[c] = acc[c];
}

// ---- aggregation layer 2: one wave per node, lanes 0..39 = classes; fused bias, writes out ----
__global__ __launch_bounds__(256) void k_agg2(
    const int* __restrict__ row_start, const int* __restrict__ sorted_src,
    const float* __restrict__ dinv, const float* __restrict__ hw2,
    const float* __restrict__ b2, float* __restrict__ out, int n)
{
    int node = blockIdx.x * 4 + (threadIdx.x >> 6);
    if (node >= n) return;
    int lane = threadIdx.x & 63;
    if (lane >= NC) return;
    int rs = row_start[node];
    int re = row_start[node + 1];
    float di = dinv[node];
    float acc = hw2[(size_t)node * NC + lane] * di * di;  // self-loop
    int k = rs;
    for (; k + 1 < re; k += 2) {
        int s0 = sorted_src[k];
        int s1 = sorted_src[k + 1];
        float w0 = dinv[s0] * di;
        float w1 = dinv[s1] * di;
        float v0 = hw2[(size_t)s0 * NC + lane];
        float v1 = hw2[(size_t)s1 * NC + lane];
        acc += v0 * w0 + v1 * w1;
    }
    if (k < re) {
        int s0 = sorted_src[k];
        acc += hw2[(size_t)s0 * NC + lane] * dinv[s0] * di;
    }
    out[(size_t)node * NC + lane] = acc + b2[lane];
}

extern "C" void kernel_launch(void* const* d_in, const int* in_sizes, int n_in,
                              void* d_out, int out_size, void* d_ws, size_t ws_size,
                              hipStream_t stream) {
    const float* x  = (const float*)d_in[0];   // f32 [N,128]
    const int* edge = (const int*)d_in[1];     // int32 [2,E]
    const float* W1 = (const float*)d_in[2];   // f32 [128,64]
    const float* b1 = (const float*)d_in[3];   // f32 [64]
    const float* W2 = (const float*)d_in[4];   // f32 [64,40]
    const float* b2 = (const float*)d_in[5];   // f32 [40]
    float* out      = (float*)d_out;           // f32 [N,40]

    const int n = in_sizes[0] / IN_CH;   // 100000
    const int e = in_sizes[1] / 2;       // 1600000
    const int* srcs = edge;
    const int* dsts = edge + e;

    // workspace layout (all 16B-aligned): ~75 MB total
    int*   counts     = (int*)d_ws;                       // NPAD
    int*   row_start  = counts + NPAD;                    // NPAD (needs n+1)
    int*   cursor     = row_start + NPAD;                 // NPAD
    int*   partials   = cursor + NPAD;                    // 512
    float* dinv       = (float*)(partials + 512);         // NPAD
    int*   sorted_src = (int*)(dinv + NPAD);              // NEDGES
    float* hw1        = (float*)(sorted_src + NEDGES);    // N*64
    float* h          = hw1 + (size_t)NNODES * HID;       // N*64
    float* hw2        = h + (size_t)NNODES * HID;         // N*40

    const int nb = (n + 255) / 256;  // 391

    hipMemsetAsync(counts, 0, (size_t)NPAD * sizeof(int), stream);
    k_hist<<<(e + 255) / 256, 256, 0, stream>>>(dsts, counts, e);
    k_scan1<<<nb, 256, 0, stream>>>(counts, row_start, partials, n);
    k_scan2<<<1, 512, 0, stream>>>(partials, nb);
    k_scan3<<<nb, 256, 0, stream>>>(counts, partials, row_start, cursor, dinv, n, e);
    k_scatter<<<(e + 255) / 256, 256, 0, stream>>>(srcs, dsts, cursor, sorted_src, e);

    k_gemm1<<<nb, 256, 0, stream>>>(x, W1, hw1, n);
    k_agg1<<<(n + 3) / 4, 256, 0, stream>>>(row_start, sorted_src, dinv, hw1, b1, h, n);
    k_gemm2<<<nb, 256, 0, stream>>>(h, W2, hw2, n);
    k_agg2<<<(n + 3) / 4, 256, 0, stream>>>(row_start, sorted_src, dinv, hw2, b2, out, n);
}

// Round 4
// 511.482 us; speedup vs baseline: 1.7398x; 1.0489x over previous
//
#include <hip/hip_runtime.h>
#include <hip/hip_bf16.h>

#define NNODES 100000
#define NEDGES 1600000
#define IN_CH 128
#define HID 64
#define NC 40
#define NPAD 100352   // NNODES padded to multiple of 256
#define NRANGE 8
#define RANGE_SZ 12500   // NNODES / 8
#define CHUNK 4096
#define NCHUNK 391       // 391*4096 = 1601536 >= NEDGES

typedef unsigned short ushort_t;

__device__ __forceinline__ float bf2f(ushort_t u) {
    union { unsigned int i; float f; } t;
    t.i = ((unsigned int)u) << 16;
    return t.f;
}
__device__ __forceinline__ ushort_t f2bf(float f) {
    union { float ff; unsigned int i; } t;
    t.ff = f;
    unsigned int r = t.i + 0x7fff + ((t.i >> 16) & 1);  // RNE
    return (ushort_t)(r >> 16);
}

// ---- CSR build: histogram of dst ----
__global__ void k_hist(const int* __restrict__ dsts, int* __restrict__ counts, int e) {
    int i = blockIdx.x * blockDim.x + threadIdx.x;
    if (i < e) atomicAdd(&counts[dsts[i]], 1);
}

// block-local exclusive scan (256 wide), block totals to partials
__global__ __launch_bounds__(256) void k_scan1(const int* __restrict__ counts,
                                               int* __restrict__ excl, int* __restrict__ partials, int n) {
    __shared__ int s[256];
    int t = threadIdx.x;
    int i = blockIdx.x * 256 + t;
    int c = (i < n) ? counts[i] : 0;
    s[t] = c;
    __syncthreads();
    for (int off = 1; off < 256; off <<= 1) {
        int v = (t >= off) ? s[t - off] : 0;
        __syncthreads();
        s[t] += v;
        __syncthreads();
    }
    if (i < n) excl[i] = s[t] - c;
    if (t == 255) partials[blockIdx.x] = s[t];
}

// scan the 391 block totals (single block)
__global__ __launch_bounds__(512) void k_scan2(int* __restrict__ partials, int nb) {
    __shared__ int s[512];
    int t = threadIdx.x;
    int c = (t < nb) ? partials[t] : 0;
    s[t] = c;
    __syncthreads();
    for (int off = 1; off < 512; off <<= 1) {
        int v = (t >= off) ? s[t - off] : 0;
        __syncthreads();
        s[t] += v;
        __syncthreads();
    }
    if (t < nb) partials[t] = s[t] - c;  // exclusive
}

// fixup: final row_start, cursor copy, dinv from counts (+1 self-loop)
__global__ void k_scan3(const int* __restrict__ counts, const int* __restrict__ partials,
                        int* __restrict__ row_start, int* __restrict__ cursor,
                        float* __restrict__ dinv, int n, int e) {
    int i = blockIdx.x * blockDim.x + threadIdx.x;
    if (i < n) {
        int rs = row_start[i] + partials[i >> 8];
        row_start[i] = rs;
        cursor[i] = rs;
        dinv[i] = rsqrtf((float)counts[i] + 1.0f);
        if (i == 0) row_start[n] = e;
    }
}

// ---- range-partitioned rank-scatter: block handles (chunk, dst-range) ----
// range = blockIdx & 7 -> XCD round-robin heuristic; writes for one range are
// confined to a 0.78 MB window of sorted_src -> L2 lines fill before eviction.
__global__ __launch_bounds__(256) void k_scatter(
    const int* __restrict__ srcs, const int* __restrict__ dsts,
    int* __restrict__ cursor, int* __restrict__ sorted_src, int e)
{
    int range = blockIdx.x & (NRANGE - 1);
    int chunk = blockIdx.x >> 3;
    int lo = range * RANGE_SZ;
    int hi = lo + RANGE_SZ;
    int begin = chunk * CHUNK;
    int end = begin + CHUNK;
    if (end > e) end = e;
    for (int i = begin + threadIdx.x; i < end; i += 256) {
        int d = dsts[i];
        if (d >= lo && d < hi) {
            int pos = atomicAdd(&cursor[d], 1);
            sorted_src[pos] = srcs[i];
        }
    }
}

// ---- GEMM1: hw1 = bf16(x @ W1) (f32 vector ALU, W1 in LDS) ----
__global__ __launch_bounds__(256) void k_gemm1(
    const float* __restrict__ x, const float* __restrict__ W1,
    ushort_t* __restrict__ hw1, int n)
{
    __shared__ float wsm[IN_CH * HID];  // 32 KB
    for (int i = threadIdx.x; i < IN_CH * HID; i += 256) wsm[i] = W1[i];
    __syncthreads();
    int row = blockIdx.x * 256 + threadIdx.x;
    if (row >= n) return;
    const float4* xr = (const float4*)(x + (size_t)row * IN_CH);
    float acc[HID];
#pragma unroll
    for (int c = 0; c < HID; ++c) acc[c] = 0.f;
#pragma unroll 4
    for (int k4 = 0; k4 < IN_CH / 4; ++k4) {
        float4 xv = xr[k4];
        const float* w0 = wsm + (k4 * 4) * HID;
#pragma unroll
        for (int c = 0; c < HID; ++c)
            acc[c] += xv.x * w0[c] + xv.y * w0[c + HID] + xv.z * w0[c + 2 * HID] + xv.w * w0[c + 3 * HID];
    }
    unsigned int* o = (unsigned int*)(hw1 + (size_t)row * HID);
#pragma unroll
    for (int c2 = 0; c2 < HID / 2; ++c2)
        o[c2] = (unsigned int)f2bf(acc[2 * c2]) | ((unsigned int)f2bf(acc[2 * c2 + 1]) << 16);
}

// ---- aggregation layer 1: one wave per node, lane = feature; fused bias+relu ----
__global__ __launch_bounds__(256) void k_agg1(
    const int* __restrict__ row_start, const int* __restrict__ sorted_src,
    const float* __restrict__ dinv, const ushort_t* __restrict__ hw1,
    const float* __restrict__ b1, float* __restrict__ h, int n)
{
    int node = blockIdx.x * 4 + (threadIdx.x >> 6);
    if (node >= n) return;
    int lane = threadIdx.x & 63;
    int rs = row_start[node];
    int re = row_start[node + 1];
    float di = dinv[node];
    float acc = bf2f(hw1[(size_t)node * HID + lane]) * di * di;  // self-loop
    int k = rs;
    for (; k + 1 < re; k += 2) {
        int s0 = sorted_src[k];
        int s1 = sorted_src[k + 1];
        float w0 = dinv[s0] * di;
        float w1 = dinv[s1] * di;
        float v0 = bf2f(hw1[(size_t)s0 * HID + lane]);
        float v1 = bf2f(hw1[(size_t)s1 * HID + lane]);
        acc += v0 * w0 + v1 * w1;
    }
    if (k < re) {
        int s0 = sorted_src[k];
        acc += bf2f(hw1[(size_t)s0 * HID + lane]) * dinv[s0] * di;
    }
    float v = acc + b1[lane];
    h[(size_t)node * HID + lane] = v > 0.f ? v : 0.f;
}

// ---- GEMM2: hw2 = bf16(h @ W2) (f32 vector ALU, W2 in LDS) ----
__global__ __launch_bounds__(256) void k_gemm2(
    const float* __restrict__ h, const float* __restrict__ W2,
    ushort_t* __restrict__ hw2, int n)
{
    __shared__ float wsm[HID * NC];  // 10 KB
    for (int i = threadIdx.x; i < HID * NC; i += 256) wsm[i] = W2[i];
    __syncthreads();
    int row = blockIdx.x * 256 + threadIdx.x;
    if (row >= n) return;
    const float4* hr = (const float4*)(h + (size_t)row * HID);
    float acc[NC];
#pragma unroll
    for (int c = 0; c < NC; ++c) acc[c] = 0.f;
#pragma unroll 4
    for (int k4 = 0; k4 < HID / 4; ++k4) {
        float4 hv = hr[k4];
        const float* w0 = wsm + (k4 * 4) * NC;
#pragma unroll
        for (int c = 0; c < NC; ++c)
            acc[c] += hv.x * w0[c] + hv.y * w0[c + NC] + hv.z * w0[c + 2 * NC] + hv.w * w0[c + 3 * NC];
    }
    unsigned int* o = (unsigned int*)(hw2 + (size_t)row * NC);
#pragma unroll
    for (int c2 = 0; c2 < NC / 2; ++c2)
        o[c2] = (unsigned int)f2bf(acc[2 * c2]) | ((unsigned int)f2bf(acc[2 * c2 + 1]) << 16);
}

// ---- aggregation layer 2: one wave per node, lanes 0..39 = classes; fused bias, writes out ----
__global__ __launch_bounds__(256) void k_agg2(
    const int* __restrict__ row_start, const int* __restrict__ sorted_src,
    const float* __restrict__ dinv, const ushort_t* __restrict__ hw2,
    const float* __restrict__ b2, float* __restrict__ out, int n)
{
    int node = blockIdx.x * 4 + (threadIdx.x >> 6);
    if (node >= n) return;
    int lane = threadIdx.x & 63;
    if (lane >= NC) return;
    int rs = row_start[node];
    int re = row_start[node + 1];
    float di = dinv[node];
    float acc = bf2f(hw2[(size_t)node * NC + lane]) * di * di;  // self-loop
    int k = rs;
    for (; k + 1 < re; k += 2) {
        int s0 = sorted_src[k];
        int s1 = sorted_src[k + 1];
        float w0 = dinv[s0] * di;
        float w1 = dinv[s1] * di;
        float v0 = bf2f(hw2[(size_t)s0 * NC + lane]);
        float v1 = bf2f(hw2[(size_t)s1 * NC + lane]);
        acc += v0 * w0 + v1 * w1;
    }
    if (k < re) {
        int s0 = sorted_src[k];
        acc += bf2f(hw2[(size_t)s0 * NC + lane]) * dinv[s0] * di;
    }
    out[(size_t)node * NC + lane] = acc + b2[lane];
}

extern "C" void kernel_launch(void* const* d_in, const int* in_sizes, int n_in,
                              void* d_out, int out_size, void* d_ws, size_t ws_size,
                              hipStream_t stream) {
    const float* x  = (const float*)d_in[0];   // f32 [N,128]
    const int* edge = (const int*)d_in[1];     // int32 [2,E]
    const float* W1 = (const float*)d_in[2];   // f32 [128,64]
    const float* b1 = (const float*)d_in[3];   // f32 [64]
    const float* W2 = (const float*)d_in[4];   // f32 [64,40]
    const float* b2 = (const float*)d_in[5];   // f32 [40]
    float* out      = (float*)d_out;           // f32 [N,40]

    const int n = in_sizes[0] / IN_CH;   // 100000
    const int e = in_sizes[1] / 2;       // 1600000
    const int* srcs = edge;
    const int* dsts = edge + e;

    // workspace layout (16B-aligned sections): ~54 MB total
    int*      counts     = (int*)d_ws;                     // NPAD
    int*      row_start  = counts + NPAD;                  // NPAD (needs n+1)
    int*      cursor     = row_start + NPAD;               // NPAD
    int*      partials   = cursor + NPAD;                  // 512
    float*    dinv       = (float*)(partials + 512);       // NPAD
    int*      sorted_src = (int*)(dinv + NPAD);            // NEDGES
    ushort_t* hw1        = (ushort_t*)(sorted_src + NEDGES);  // N*64 bf16
    float*    h          = (float*)(hw1 + (size_t)NNODES * HID); // N*64 f32
    ushort_t* hw2        = (ushort_t*)(h + (size_t)NNODES * HID); // N*40 bf16

    const int nb = (n + 255) / 256;  // 391

    hipMemsetAsync(counts, 0, (size_t)NPAD * sizeof(int), stream);
    k_hist<<<(e + 255) / 256, 256, 0, stream>>>(dsts, counts, e);
    k_scan1<<<nb, 256, 0, stream>>>(counts, row_start, partials, n);
    k_scan2<<<1, 512, 0, stream>>>(partials, nb);
    k_scan3<<<nb, 256, 0, stream>>>(counts, partials, row_start, cursor, dinv, n, e);
    k_scatter<<<NCHUNK * NRANGE, 256, 0, stream>>>(srcs, dsts, cursor, sorted_src, e);

    k_gemm1<<<nb, 256, 0, stream>>>(x, W1, hw1, n);
    k_agg1<<<(n + 3) / 4, 256, 0, stream>>>(row_start, sorted_src, dinv, hw1, b1, h, n);
    k_gemm2<<<nb, 256, 0, stream>>>(h, W2, hw2, n);
    k_agg2<<<(n + 3) / 4, 256, 0, stream>>>(row_start, sorted_src, dinv, hw2, b2, out, n);
}

// Round 5
// 430.337 us; speedup vs baseline: 2.0678x; 1.1886x over previous
//
#include <hip/hip_runtime.h>
#include <hip/hip_bf16.h>

#define NNODES 100000
#define NEDGES 1600000
#define IN_CH 128
#define HID 64
#define NC 40
#define NPAD 100352   // NNODES padded to multiple of 256
#define NRANGE 8
#define RANGE_SZ 12500   // NNODES / 8
#define CHUNK 4096
#define NCHUNK 391       // 391*4096 = 1601536 >= NEDGES

typedef unsigned short ushort_t;
typedef __attribute__((ext_vector_type(8))) short short8;
typedef __attribute__((ext_vector_type(4))) float floatx4;

__device__ __forceinline__ float bf2f(ushort_t u) {
    union { unsigned int i; float f; } t;
    t.i = ((unsigned int)u) << 16;
    return t.f;
}
__device__ __forceinline__ ushort_t f2bf(float f) {
    union { float ff; unsigned int i; } t;
    t.ff = f;
    unsigned int r = t.i + 0x7fff + ((t.i >> 16) & 1);  // RNE
    return (ushort_t)(r >> 16);
}

// ---- CSR build: histogram of dst ----
__global__ void k_hist(const int* __restrict__ dsts, int* __restrict__ counts, int e) {
    int i = blockIdx.x * blockDim.x + threadIdx.x;
    if (i < e) atomicAdd(&counts[dsts[i]], 1);
}

// block-local exclusive scan (256 wide), block totals to partials
__global__ __launch_bounds__(256) void k_scan1(const int* __restrict__ counts,
                                               int* __restrict__ excl, int* __restrict__ partials, int n) {
    __shared__ int s[256];
    int t = threadIdx.x;
    int i = blockIdx.x * 256 + t;
    int c = (i < n) ? counts[i] : 0;
    s[t] = c;
    __syncthreads();
    for (int off = 1; off < 256; off <<= 1) {
        int v = (t >= off) ? s[t - off] : 0;
        __syncthreads();
        s[t] += v;
        __syncthreads();
    }
    if (i < n) excl[i] = s[t] - c;
    if (t == 255) partials[blockIdx.x] = s[t];
}

// scan the 391 block totals (single block)
__global__ __launch_bounds__(512) void k_scan2(int* __restrict__ partials, int nb) {
    __shared__ int s[512];
    int t = threadIdx.x;
    int c = (t < nb) ? partials[t] : 0;
    s[t] = c;
    __syncthreads();
    for (int off = 1; off < 512; off <<= 1) {
        int v = (t >= off) ? s[t - off] : 0;
        __syncthreads();
        s[t] += v;
        __syncthreads();
    }
    if (t < nb) partials[t] = s[t] - c;  // exclusive
}

// fixup: final row_start, cursor copy, dinv from counts (+1 self-loop)
__global__ void k_scan3(const int* __restrict__ counts, const int* __restrict__ partials,
                        int* __restrict__ row_start, int* __restrict__ cursor,
                        float* __restrict__ dinv, int n, int e) {
    int i = blockIdx.x * blockDim.x + threadIdx.x;
    if (i < n) {
        int rs = row_start[i] + partials[i >> 8];
        row_start[i] = rs;
        cursor[i] = rs;
        dinv[i] = rsqrtf((float)counts[i] + 1.0f);
        if (i == 0) row_start[n] = e;
    }
}

// ---- range-partitioned rank-scatter; stores packed (src, weight) ----
// range = blockIdx & 7 -> XCD round-robin; writes confined to a 1.6 MB window.
__global__ __launch_bounds__(256) void k_scatter(
    const int* __restrict__ srcs, const int* __restrict__ dsts,
    const float* __restrict__ dinv,
    int* __restrict__ cursor, int2* __restrict__ ew, int e)
{
    int range = blockIdx.x & (NRANGE - 1);
    int chunk = blockIdx.x >> 3;
    int lo = range * RANGE_SZ;
    int hi = lo + RANGE_SZ;
    int begin = chunk * CHUNK;
    int end = begin + CHUNK;
    if (end > e) end = e;
    for (int i = begin + threadIdx.x; i < end; i += 256) {
        int d = dsts[i];
        if (d >= lo && d < hi) {
            int s = srcs[i];
            float w = dinv[s] * dinv[d];
            int pos = atomicAdd(&cursor[d], 1);
            ew[pos] = make_int2(s, __float_as_int(w));
        }
    }
}

// ---- pre-swizzle W1 (f32) into bf16 B-fragment order ----
// dest index: (((kc*4+quad)*4+ct)*16+m)*8+j  <-  W1[(kc*32+quad*8+j)*64 + ct*16+m]
__global__ void k_prepw(const float* __restrict__ W1, ushort_t* __restrict__ Wp) {
    int i = blockIdx.x * 256 + threadIdx.x;
    if (i >= IN_CH * HID) return;
    int j = i & 7;
    int m = (i >> 3) & 15;
    int ct = (i >> 7) & 3;
    int quad = (i >> 9) & 3;
    int kc = i >> 11;
    int k = kc * 32 + quad * 8 + j;
    int c = ct * 16 + m;
    Wp[i] = f2bf(W1[k * HID + c]);
}

// ---- GEMM1: hw1 = bf16(x @ W1) via MFMA (bf16 in, f32 acc) ----
// block = 4 waves; wave computes 16 rows x 64 cols, K=128 in 4 slabs of 32.
// A-frag: A[m=lane&15][k=quad*8+j]; C/D: col=lane&15, row=quad*4+reg (m89/m91).
__global__ __launch_bounds__(256) void k_gemm1(
    const float* __restrict__ x, const ushort_t* __restrict__ Wp,
    ushort_t* __restrict__ hw1, int n)
{
    int wave = threadIdx.x >> 6;
    int lane = threadIdx.x & 63;
    int m = lane & 15;
    int quad = lane >> 4;
    int row = blockIdx.x * 64 + wave * 16 + m;
    int rowc = row < n ? row : (n - 1);
    const float* xr = x + (size_t)rowc * IN_CH + quad * 8;

    floatx4 acc[4];
#pragma unroll
    for (int ct = 0; ct < 4; ++ct) acc[ct] = (floatx4){0.f, 0.f, 0.f, 0.f};

#pragma unroll
    for (int kc = 0; kc < 4; ++kc) {
        float4 xa = *(const float4*)(xr + kc * 32);
        float4 xb = *(const float4*)(xr + kc * 32 + 4);
        short8 a;
        a[0] = (short)f2bf(xa.x); a[1] = (short)f2bf(xa.y);
        a[2] = (short)f2bf(xa.z); a[3] = (short)f2bf(xa.w);
        a[4] = (short)f2bf(xb.x); a[5] = (short)f2bf(xb.y);
        a[6] = (short)f2bf(xb.z); a[7] = (short)f2bf(xb.w);
#pragma unroll
        for (int ct = 0; ct < 4; ++ct) {
            short8 b = *(const short8*)(Wp + ((((kc * 4 + quad) * 4 + ct) * 16 + m) << 3));
            acc[ct] = __builtin_amdgcn_mfma_f32_16x16x32_bf16(a, b, acc[ct], 0, 0, 0);
        }
    }
    int r0 = blockIdx.x * 64 + wave * 16 + quad * 4;
#pragma unroll
    for (int r = 0; r < 4; ++r) {
        int rr = r0 + r;
        if (rr < n) {
            ushort_t* o = hw1 + (size_t)rr * HID + m;
#pragma unroll
            for (int ct = 0; ct < 4; ++ct) o[ct * 16] = f2bf(acc[ct][r]);
        }
    }
}

// ---- aggregation layer 1: one wave per node, lane = feature; 8-deep gather MLP ----
__global__ __launch_bounds__(256) void k_agg1(
    const int* __restrict__ row_start, const int2* __restrict__ ew,
    const float* __restrict__ dinv, const ushort_t* __restrict__ hw1,
    const float* __restrict__ b1, float* __restrict__ h, int n)
{
    int node = blockIdx.x * 4 + (threadIdx.x >> 6);
    if (node >= n) return;
    int lane = threadIdx.x & 63;
    int rs = row_start[node];
    int re = row_start[node + 1];
    float di = dinv[node];
    float acc0 = bf2f(hw1[node * HID + lane]) * di * di;  // self-loop
    float acc1 = 0.f, acc2 = 0.f, acc3 = 0.f;
    int k = rs;
    for (; k + 7 < re; k += 8) {
        int2 e0 = ew[k],     e1 = ew[k + 1], e2 = ew[k + 2], e3 = ew[k + 3];
        int2 e4 = ew[k + 4], e5 = ew[k + 5], e6 = ew[k + 6], e7 = ew[k + 7];
        float v0 = bf2f(hw1[e0.x * HID + lane]);
        float v1 = bf2f(hw1[e1.x * HID + lane]);
        float v2 = bf2f(hw1[e2.x * HID + lane]);
        float v3 = bf2f(hw1[e3.x * HID + lane]);
        float v4 = bf2f(hw1[e4.x * HID + lane]);
        float v5 = bf2f(hw1[e5.x * HID + lane]);
        float v6 = bf2f(hw1[e6.x * HID + lane]);
        float v7 = bf2f(hw1[e7.x * HID + lane]);
        acc0 += v0 * __int_as_float(e0.y);
        acc1 += v1 * __int_as_float(e1.y);
        acc2 += v2 * __int_as_float(e2.y);
        acc3 += v3 * __int_as_float(e3.y);
        acc0 += v4 * __int_as_float(e4.y);
        acc1 += v5 * __int_as_float(e5.y);
        acc2 += v6 * __int_as_float(e6.y);
        acc3 += v7 * __int_as_float(e7.y);
    }
    for (; k < re; ++k) {
        int2 e0 = ew[k];
        acc1 += bf2f(hw1[e0.x * HID + lane]) * __int_as_float(e0.y);
    }
    float v = (acc0 + acc1) + (acc2 + acc3) + b1[lane];
    h[(size_t)node * HID + lane] = v > 0.f ? v : 0.f;
}

// ---- GEMM2: hw2 = bf16(h @ W2) (f32 vector ALU, W2 in LDS) ----
__global__ __launch_bounds__(256) void k_gemm2(
    const float* __restrict__ h, const float* __restrict__ W2,
    ushort_t* __restrict__ hw2, int n)
{
    __shared__ float wsm[HID * NC];  // 10 KB
    for (int i = threadIdx.x; i < HID * NC; i += 256) wsm[i] = W2[i];
    __syncthreads();
    int row = blockIdx.x * 256 + threadIdx.x;
    if (row >= n) return;
    const float4* hr = (const float4*)(h + (size_t)row * HID);
    float acc[NC];
#pragma unroll
    for (int c = 0; c < NC; ++c) acc[c] = 0.f;
#pragma unroll 4
    for (int k4 = 0; k4 < HID / 4; ++k4) {
        float4 hv = hr[k4];
        const float* w0 = wsm + (k4 * 4) * NC;
#pragma unroll
        for (int c = 0; c < NC; ++c)
            acc[c] += hv.x * w0[c] + hv.y * w0[c + NC] + hv.z * w0[c + 2 * NC] + hv.w * w0[c + 3 * NC];
    }
    unsigned int* o = (unsigned int*)(hw2 + (size_t)row * NC);
#pragma unroll
    for (int c2 = 0; c2 < NC / 2; ++c2)
        o[c2] = (unsigned int)f2bf(acc[2 * c2]) | ((unsigned int)f2bf(acc[2 * c2 + 1]) << 16);
}

// ---- aggregation layer 2: one wave per node, lanes 0..39; 8-deep gather MLP ----
__global__ __launch_bounds__(256) void k_agg2(
    const int* __restrict__ row_start, const int2* __restrict__ ew,
    const float* __restrict__ dinv, const ushort_t* __restrict__ hw2,
    const float* __restrict__ b2, float* __restrict__ out, int n)
{
    int node = blockIdx.x * 4 + (threadIdx.x >> 6);
    if (node >= n) return;
    int lane = threadIdx.x & 63;
    if (lane >= NC) return;
    int rs = row_start[node];
    int re = row_start[node + 1];
    float di = dinv[node];
    float acc0 = bf2f(hw2[node * NC + lane]) * di * di;  // self-loop
    float acc1 = 0.f, acc2 = 0.f, acc3 = 0.f;
    int k = rs;
    for (; k + 7 < re; k += 8) {
        int2 e0 = ew[k],     e1 = ew[k + 1], e2 = ew[k + 2], e3 = ew[k + 3];
        int2 e4 = ew[k + 4], e5 = ew[k + 5], e6 = ew[k + 6], e7 = ew[k + 7];
        float v0 = bf2f(hw2[e0.x * NC + lane]);
        float v1 = bf2f(hw2[e1.x * NC + lane]);
        float v2 = bf2f(hw2[e2.x * NC + lane]);
        float v3 = bf2f(hw2[e3.x * NC + lane]);
        float v4 = bf2f(hw2[e4.x * NC + lane]);
        float v5 = bf2f(hw2[e5.x * NC + lane]);
        float v6 = bf2f(hw2[e6.x * NC + lane]);
        float v7 = bf2f(hw2[e7.x * NC + lane]);
        acc0 += v0 * __int_as_float(e0.y);
        acc1 += v1 * __int_as_float(e1.y);
        acc2 += v2 * __int_as_float(e2.y);
        acc3 += v3 * __int_as_float(e3.y);
        acc0 += v4 * __int_as_float(e4.y);
        acc1 += v5 * __int_as_float(e5.y);
        acc2 += v6 * __int_as_float(e6.y);
        acc3 += v7 * __int_as_float(e7.y);
    }
    for (; k < re; ++k) {
        int2 e0 = ew[k];
        acc1 += bf2f(hw2[e0.x * NC + lane]) * __int_as_float(e0.y);
    }
    out[(size_t)node * NC + lane] = (acc0 + acc1) + (acc2 + acc3) + b2[lane];
}

extern "C" void kernel_launch(void* const* d_in, const int* in_sizes, int n_in,
                              void* d_out, int out_size, void* d_ws, size_t ws_size,
                              hipStream_t stream) {
    const float* x  = (const float*)d_in[0];   // f32 [N,128]
    const int* edge = (const int*)d_in[1];     // int32 [2,E]
    const float* W1 = (const float*)d_in[2];   // f32 [128,64]
    const float* b1 = (const float*)d_in[3];   // f32 [64]
    const float* W2 = (const float*)d_in[4];   // f32 [64,40]
    const float* b2 = (const float*)d_in[5];   // f32 [40]
    float* out      = (float*)d_out;           // f32 [N,40]

    const int n = in_sizes[0] / IN_CH;   // 100000
    const int e = in_sizes[1] / 2;       // 1600000
    const int* srcs = edge;
    const int* dsts = edge + e;

    // workspace layout: ~62 MB total
    int*      counts    = (int*)d_ws;                       // NPAD
    int*      row_start = counts + NPAD;                    // NPAD (needs n+1)
    int*      cursor    = row_start + NPAD;                 // NPAD
    int*      partials  = cursor + NPAD;                    // 512
    float*    dinv      = (float*)(partials + 512);         // NPAD
    int2*     ew        = (int2*)(dinv + NPAD);             // NEDGES (src, w) 8B; 8-aligned
    ushort_t* Wp        = (ushort_t*)(ew + NEDGES);         // 8192 bf16
    ushort_t* hw1       = Wp + 8192;                        // N*64 bf16
    float*    h         = (float*)(hw1 + (size_t)NNODES * HID); // N*64 f32
    ushort_t* hw2       = (ushort_t*)(h + (size_t)NNODES * HID); // N*40 bf16

    const int nb = (n + 255) / 256;  // 391

    hipMemsetAsync(counts, 0, (size_t)NPAD * sizeof(int), stream);
    k_hist<<<(e + 255) / 256, 256, 0, stream>>>(dsts, counts, e);
    k_scan1<<<nb, 256, 0, stream>>>(counts, row_start, partials, n);
    k_scan2<<<1, 512, 0, stream>>>(partials, nb);
    k_scan3<<<nb, 256, 0, stream>>>(counts, partials, row_start, cursor, dinv, n, e);
    k_scatter<<<NCHUNK * NRANGE, 256, 0, stream>>>(srcs, dsts, dinv, cursor, ew, e);

    k_prepw<<<32, 256, 0, stream>>>(W1, Wp);
    k_gemm1<<<(n + 63) / 64, 256, 0, stream>>>(x, Wp, hw1, n);
    k_agg1<<<(n + 3) / 4, 256, 0, stream>>>(row_start, ew, dinv, hw1, b1, h, n);
    k_gemm2<<<nb, 256, 0, stream>>>(h, W2, hw2, n);
    k_agg2<<<(n + 3) / 4, 256, 0, stream>>>(row_start, ew, dinv, hw2, b2, out, n);
}